// Round 4
// baseline (158.767 us; speedup 1.0000x reference)
//
#include <hip/hip_runtime.h>
#include <math.h>

#define NACC 32
// acc layout: 0 cnt, 1 sw, 2-4 swx, 5-7 swy, 8-16 swyx[o*3+i],
//             17-19 sx, 20-22 sy, 23-31 syx[o*3+i]

__device__ __forceinline__ void accum_point(float w, float x0, float x1, float x2,
                                            float y0, float y1, float y2, float* a) {
    a[0] += (w > 0.0f) ? 1.0f : 0.0f;
    a[1] += w;
    a[2] = fmaf(w, x0, a[2]); a[3] = fmaf(w, x1, a[3]); a[4] = fmaf(w, x2, a[4]);
    float wy0 = w * y0, wy1 = w * y1, wy2 = w * y2;
    a[5] += wy0; a[6] += wy1; a[7] += wy2;
    a[8]  = fmaf(wy0, x0, a[8]);  a[9]  = fmaf(wy0, x1, a[9]);  a[10] = fmaf(wy0, x2, a[10]);
    a[11] = fmaf(wy1, x0, a[11]); a[12] = fmaf(wy1, x1, a[12]); a[13] = fmaf(wy1, x2, a[13]);
    a[14] = fmaf(wy2, x0, a[14]); a[15] = fmaf(wy2, x1, a[15]); a[16] = fmaf(wy2, x2, a[16]);
    a[17] += x0; a[18] += x1; a[19] += x2;
    a[20] += y0; a[21] += y1; a[22] += y2;
    a[23] = fmaf(y0, x0, a[23]); a[24] = fmaf(y0, x1, a[24]); a[25] = fmaf(y0, x2, a[25]);
    a[26] = fmaf(y1, x0, a[26]); a[27] = fmaf(y1, x1, a[27]); a[28] = fmaf(y1, x2, a[28]);
    a[29] = fmaf(y2, x0, a[29]); a[30] = fmaf(y2, x1, a[30]); a[31] = fmaf(y2, x2, a[31]);
}

// consume one 4-point group given its 7 float4s (3 A + 3 B + 1 w)
__device__ __forceinline__ void accum_group(float4 wv, float4 x0, float4 x1, float4 x2,
                                            float4 y0, float4 y1, float4 y2, float* a) {
    accum_point(wv.x, x0.x, x0.y, x0.z, y0.x, y0.y, y0.z, a);
    accum_point(wv.y, x0.w, x1.x, x1.y, y0.w, y1.x, y1.y, a);
    accum_point(wv.z, x1.z, x1.w, x2.x, y1.z, y1.w, y2.x, a);
    accum_point(wv.w, x2.y, x2.z, x2.w, y2.y, y2.z, y2.w, a);
}

__global__ __launch_bounds__(256) void kabsch_reduce(
    const float* __restrict__ c0, const float* __restrict__ c1,
    const float* __restrict__ w, int N, float* __restrict__ partials, int nblocks) {
    __shared__ float wred[4][NACC];

    float a[NACC];
    #pragma unroll
    for (int i = 0; i < NACC; ++i) a[i] = 0.0f;

    const int t = threadIdx.x;
    const int lane = t & 63, wave = t >> 6;
    const int tid = blockIdx.x * blockDim.x + t;
    const int nthreads = gridDim.x * blockDim.x;
    const int ngroups = N >> 2;       // 4-point groups (48B -> 3 aligned float4s)
    const int npairs = ngroups >> 1;  // a "pair" = 2 groups = 8 points
    const float4* A4 = (const float4*)c0;
    const float4* B4 = (const float4*)c1;
    const float4* W4 = (const float4*)w;

    // two independent pair-slots per loop body, strided nthreads apart:
    // 14 float4 loads issued before any accumulate -> deep MLP, no barriers.
    for (int p0 = tid; p0 < npairs; p0 += 2 * nthreads) {
        int p1 = p0 + nthreads;
        bool have1 = p1 < npairs;
        size_t b0 = (size_t)6 * (size_t)p0;
        size_t b1 = have1 ? (size_t)6 * (size_t)p1 : b0;

        float4 w0a = W4[p0 * 2], w0b = W4[p0 * 2 + 1];
        float4 a00 = A4[b0],     a01 = A4[b0 + 1], a02 = A4[b0 + 2];
        float4 a03 = A4[b0 + 3], a04 = A4[b0 + 4], a05 = A4[b0 + 5];
        float4 b00 = B4[b0],     b01 = B4[b0 + 1], b02 = B4[b0 + 2];
        float4 b03 = B4[b0 + 3], b04 = B4[b0 + 4], b05 = B4[b0 + 5];
        float4 w1a = W4[(have1 ? p1 : p0) * 2], w1b = W4[(have1 ? p1 : p0) * 2 + 1];
        float4 a10 = A4[b1],     a11 = A4[b1 + 1], a12 = A4[b1 + 2];
        float4 a13 = A4[b1 + 3], a14 = A4[b1 + 4], a15 = A4[b1 + 5];
        float4 b10 = B4[b1],     b11 = B4[b1 + 1], b12 = B4[b1 + 2];
        float4 b13 = B4[b1 + 3], b14 = B4[b1 + 4], b15 = B4[b1 + 5];

        accum_group(w0a, a00, a01, a02, b00, b01, b02, a);
        accum_group(w0b, a03, a04, a05, b03, b04, b05, a);
        if (have1) {
            accum_group(w1a, a10, a11, a12, b10, b11, b12, a);
            accum_group(w1b, a13, a14, a15, b13, b14, b15, a);
        }
    }
    if (tid == 0) {  // tails: odd trailing group + non-multiple-of-4 points
        if (npairs * 2 < ngroups) {
            int g = npairs * 2;
            size_t base = (size_t)3 * (size_t)g;
            accum_group(W4[g], A4[base], A4[base + 1], A4[base + 2],
                        B4[base], B4[base + 1], B4[base + 2], a);
        }
        for (int i = ngroups << 2; i < N; ++i)
            accum_point(w[i], c0[3*i], c0[3*i+1], c0[3*i+2],
                        c1[3*i], c1[3*i+1], c1[3*i+2], a);
    }

    // ---- multi-value butterfly wave reduction: 32 accs in 32 shuffles.
    // final mapping lane -> acc = bitrev5(lane&31). ----
    {
        int hi;
        hi = lane & 1;
        #pragma unroll
        for (int i = 0; i < 16; ++i) {
            float send = hi ? a[i] : a[i + 16];
            float recv = __shfl_xor(send, 1, 64);
            a[i] = (hi ? a[i + 16] : a[i]) + recv;
        }
        hi = lane & 2;
        #pragma unroll
        for (int i = 0; i < 8; ++i) {
            float send = hi ? a[i] : a[i + 8];
            float recv = __shfl_xor(send, 2, 64);
            a[i] = (hi ? a[i + 8] : a[i]) + recv;
        }
        hi = lane & 4;
        #pragma unroll
        for (int i = 0; i < 4; ++i) {
            float send = hi ? a[i] : a[i + 4];
            float recv = __shfl_xor(send, 4, 64);
            a[i] = (hi ? a[i + 4] : a[i]) + recv;
        }
        hi = lane & 8;
        #pragma unroll
        for (int i = 0; i < 2; ++i) {
            float send = hi ? a[i] : a[i + 2];
            float recv = __shfl_xor(send, 8, 64);
            a[i] = (hi ? a[i + 2] : a[i]) + recv;
        }
        hi = lane & 16;
        {
            float send = hi ? a[0] : a[1];
            float recv = __shfl_xor(send, 16, 64);
            a[0] = (hi ? a[1] : a[0]) + recv;
        }
        a[0] += __shfl_xor(a[0], 32, 64);
    }
    if (lane < 32) {
        int acc = ((lane & 1) << 4) | ((lane & 2) << 2) | (lane & 4)
                | ((lane & 8) >> 2) | ((lane & 16) >> 4);  // bitrev5
        wred[wave][acc] = a[0];
    }
    __syncthreads();
    if (t < NACC)
        partials[t * nblocks + blockIdx.x] =
            wred[0][t] + wred[1][t] + wred[2][t] + wred[3][t];
}

__device__ __forceinline__ double det3(const double m[3][3]) {
    return m[0][0] * (m[1][1] * m[2][2] - m[1][2] * m[2][1])
         - m[0][1] * (m[1][0] * m[2][2] - m[1][2] * m[2][0])
         + m[0][2] * (m[1][0] * m[2][1] - m[1][1] * m[2][0]);
}

__global__ __launch_bounds__(256) void kabsch_finalize(
    const float* __restrict__ partials, int nblocks, int N, float* __restrict__ out) {
    double d[NACC];
    #pragma unroll
    for (int i = 0; i < NACC; ++i) d[i] = 0.0;
    for (int m = threadIdx.x; m < nblocks; m += 256) {
        #pragma unroll
        for (int i = 0; i < NACC; ++i)
            d[i] += (double)partials[i * nblocks + m];   // lane-contiguous per i
    }
    #pragma unroll
    for (int off = 32; off > 0; off >>= 1) {
        #pragma unroll
        for (int i = 0; i < NACC; ++i) d[i] += __shfl_down(d[i], off, 64);
    }
    __shared__ double sm[4][NACC];
    int wave = threadIdx.x >> 6, lane = threadIdx.x & 63;
    if (lane == 0) {
        #pragma unroll
        for (int i = 0; i < NACC; ++i) sm[wave][i] = d[i];
    }
    __syncthreads();
    if (threadIdx.x != 0) return;
    #pragma unroll
    for (int i = 0; i < NACC; ++i) d[i] = sm[0][i] + sm[1][i] + sm[2][i] + sm[3][i];

    const double EPSF = (double)1.1920929e-7f;  // float32 eps
    double cnt = d[0];
    double W = d[1];
    double swx[3] = { d[2], d[3], d[4] };
    double swy[3] = { d[5], d[6], d[7] };
    double swyx[9];
    for (int i = 0; i < 9; ++i) swyx[i] = d[8 + i];
    bool nep = cnt < 3.0;
    if (nep) {  // weights += EPS everywhere, applied analytically
        W += EPSF * (double)N;
        for (int i = 0; i < 3; ++i) { swx[i] += EPSF * d[17 + i]; swy[i] += EPSF * d[20 + i]; }
        for (int i = 0; i < 9; ++i) swyx[i] += EPSF * d[23 + i];
    }

    double mx[3], my[3];
    for (int i = 0; i < 3; ++i) { mx[i] = swx[i] / W; my[i] = swy[i] / W; }
    double S[3][3];
    for (int o = 0; o < 3; ++o)
        for (int i = 0; i < 3; ++i)
            S[o][i] = swyx[o * 3 + i] / W - my[o] * mx[i];

    // Jacobi eigendecomposition of B = S^T S -> V, lam. Fixed 6 cyclic sweeps
    // (quadratic convergence: far past double precision for 3x3), no serial
    // convergence test.
    double Bm[3][3], V[3][3];
    for (int i = 0; i < 3; ++i)
        for (int j = 0; j < 3; ++j) {
            double acc = 0.0;
            for (int k = 0; k < 3; ++k) acc += S[k][i] * S[k][j];
            Bm[i][j] = acc;
            V[i][j] = (i == j) ? 1.0 : 0.0;
        }
    for (int sweep = 0; sweep < 6; ++sweep) {
        for (int pair = 0; pair < 3; ++pair) {
            int p = (pair == 2) ? 1 : 0;
            int q = (pair == 0) ? 1 : 2;
            double apq = Bm[p][q];
            if (fabs(apq) < 1e-300) continue;
            double theta = (Bm[q][q] - Bm[p][p]) / (2.0 * apq);
            double tt = ((theta >= 0.0) ? 1.0 : -1.0) / (fabs(theta) + sqrt(1.0 + theta * theta));
            double c = 1.0 / sqrt(1.0 + tt * tt);
            double sn = tt * c;
            for (int k = 0; k < 3; ++k) {
                double bkp = Bm[k][p], bkq = Bm[k][q];
                Bm[k][p] = c * bkp - sn * bkq;
                Bm[k][q] = sn * bkp + c * bkq;
            }
            for (int k = 0; k < 3; ++k) {
                double bpk = Bm[p][k], bqk = Bm[q][k];
                Bm[p][k] = c * bpk - sn * bqk;
                Bm[q][k] = sn * bpk + c * bqk;
            }
            for (int k = 0; k < 3; ++k) {
                double vkp = V[k][p], vkq = V[k][q];
                V[k][p] = c * vkp - sn * vkq;
                V[k][q] = sn * vkp + c * vkq;
            }
        }
    }
    double lam[3] = { Bm[0][0], Bm[1][1], Bm[2][2] };
    for (int i = 0; i < 2; ++i)
        for (int j = i + 1; j < 3; ++j)
            if (lam[j] > lam[i]) {
                double tl = lam[i]; lam[i] = lam[j]; lam[j] = tl;
                for (int k = 0; k < 3; ++k) { double tv = V[k][i]; V[k][i] = V[k][j]; V[k][j] = tv; }
            }
    double sig[3];
    for (int i = 0; i < 3; ++i) sig[i] = sqrt(fmax(lam[i], 0.0));

    double U[3][3];
    for (int i = 0; i < 3; ++i) {
        double u0 = S[0][0]*V[0][i] + S[0][1]*V[1][i] + S[0][2]*V[2][i];
        double u1 = S[1][0]*V[0][i] + S[1][1]*V[1][i] + S[1][2]*V[2][i];
        double u2 = S[2][0]*V[0][i] + S[2][1]*V[1][i] + S[2][2]*V[2][i];
        double nrm = sqrt(u0*u0 + u1*u1 + u2*u2);
        if (nrm > 1e-150) {
            U[0][i] = u0 / nrm; U[1][i] = u1 / nrm; U[2][i] = u2 / nrm;
        } else if (i == 0) {
            U[0][0] = 1.0; U[1][0] = 0.0; U[2][0] = 0.0;
        } else if (i == 1) {
            double e0 = (fabs(U[0][0]) < 0.9) ? 1.0 : 0.0;
            double e1 = 1.0 - e0;
            double dp = e0 * U[0][0] + e1 * U[1][0];
            double v0 = e0 - dp * U[0][0], v1 = e1 - dp * U[1][0], v2 = -dp * U[2][0];
            double n2 = sqrt(v0*v0 + v1*v1 + v2*v2);
            U[0][1] = v0 / n2; U[1][1] = v1 / n2; U[2][1] = v2 / n2;
        } else {
            U[0][2] = U[1][0]*U[2][1] - U[2][0]*U[1][1];
            U[1][2] = U[2][0]*U[0][1] - U[0][0]*U[2][1];
            U[2][2] = U[0][0]*U[1][1] - U[1][0]*U[0][1];
        }
    }

    double tol = sig[0] * 3.0 * EPSF;
    int rank = (sig[0] > tol) + (sig[1] > tol) + (sig[2] > tol);
    double detS = det3(S);
    double det_mul = det3(U) * det3(V);
    double sign_full = (detS < 0.0) ? -1.0 : 1.0;
    double sign_def = (fabs(det_mul + 1.0) <= 1.00001e-5) ? -1.0 : 1.0;
    double s = (rank > 2) ? sign_full : sign_def;

    double R[3][3];
    for (int o = 0; o < 3; ++o)
        for (int i = 0; i < 3; ++i)
            R[o][i] = U[o][0]*V[i][0] + U[o][1]*V[i][1] + s * U[o][2]*V[i][2];
    double tv[3];
    for (int o = 0; o < 3; ++o)
        tv[o] = my[o] - (R[o][0]*mx[0] + R[o][1]*mx[1] + R[o][2]*mx[2]);

    for (int o = 0; o < 3; ++o) {
        out[o * 4 + 0] = (float)R[o][0];
        out[o * 4 + 1] = (float)R[o][1];
        out[o * 4 + 2] = (float)R[o][2];
        out[o * 4 + 3] = (float)tv[o];
    }
    out[12] = 0.0f; out[13] = 0.0f; out[14] = 0.0f; out[15] = 1.0f;
    out[16] = nep ? 1.0f : 0.0f;
}

extern "C" void kernel_launch(void* const* d_in, const int* in_sizes, int n_in,
                              void* d_out, int out_size, void* d_ws, size_t ws_size,
                              hipStream_t stream) {
    const float* c0 = (const float*)d_in[0];
    const float* c1 = (const float*)d_in[1];
    const float* w  = (const float*)d_in[2];
    float* out = (float*)d_out;
    int N = in_sizes[2];  // B=1: weights has N elements

    int blocks = 1024;   // 4 blocks/CU, no LDS tiles -> VGPR-limited occupancy
    size_t need = (size_t)blocks * NACC * sizeof(float);
    if (need > ws_size) {
        blocks = (int)(ws_size / (NACC * sizeof(float)));
        if (blocks < 1) blocks = 1;
    }
    float* partials = (float*)d_ws;   // layout: [acc][block] (transposed)

    kabsch_reduce<<<blocks, 256, 0, stream>>>(c0, c1, w, N, partials, blocks);
    kabsch_finalize<<<1, 256, 0, stream>>>(partials, blocks, N, out);
}

// Round 5
// 155.938 us; speedup vs baseline: 1.0181x; 1.0181x over previous
//
#include <hip/hip_runtime.h>
#include <math.h>

#define NACC 32
// partials layout (32 slots/block):
//  main (always valid):   0 cnt, 1 sw, 2-4 swx, 5-7 swy, 8-16 swyx[o*3+i]
//  fallback (valid only when block-local cnt<3, else zeros):
//                         17-19 sx, 20-22 sy, 23-31 syx[o*3+i]
#define NMAIN 17
#define NFALL 15

__device__ __forceinline__ void accum_main(float w, float x0, float x1, float x2,
                                           float y0, float y1, float y2, float* a) {
    a[0] += (w > 0.0f) ? 1.0f : 0.0f;
    a[1] += w;
    a[2] = fmaf(w, x0, a[2]); a[3] = fmaf(w, x1, a[3]); a[4] = fmaf(w, x2, a[4]);
    float wy0 = w * y0, wy1 = w * y1, wy2 = w * y2;
    a[5] += wy0; a[6] += wy1; a[7] += wy2;
    a[8]  = fmaf(wy0, x0, a[8]);  a[9]  = fmaf(wy0, x1, a[9]);  a[10] = fmaf(wy0, x2, a[10]);
    a[11] = fmaf(wy1, x0, a[11]); a[12] = fmaf(wy1, x1, a[12]); a[13] = fmaf(wy1, x2, a[13]);
    a[14] = fmaf(wy2, x0, a[14]); a[15] = fmaf(wy2, x1, a[15]); a[16] = fmaf(wy2, x2, a[16]);
}

__device__ __forceinline__ void accum_fall(float x0, float x1, float x2,
                                           float y0, float y1, float y2, float* f) {
    f[0] += x0; f[1] += x1; f[2] += x2;
    f[3] += y0; f[4] += y1; f[5] += y2;
    f[6]  = fmaf(y0, x0, f[6]);  f[7]  = fmaf(y0, x1, f[7]);  f[8]  = fmaf(y0, x2, f[8]);
    f[9]  = fmaf(y1, x0, f[9]);  f[10] = fmaf(y1, x1, f[10]); f[11] = fmaf(y1, x2, f[11]);
    f[12] = fmaf(y2, x0, f[12]); f[13] = fmaf(y2, x1, f[13]); f[14] = fmaf(y2, x2, f[14]);
}

__device__ __forceinline__ void accum_group_main(float4 wv, float4 x0, float4 x1, float4 x2,
                                                 float4 y0, float4 y1, float4 y2, float* a) {
    accum_main(wv.x, x0.x, x0.y, x0.z, y0.x, y0.y, y0.z, a);
    accum_main(wv.y, x0.w, x1.x, x1.y, y0.w, y1.x, y1.y, a);
    accum_main(wv.z, x1.z, x1.w, x2.x, y1.z, y1.w, y2.x, a);
    accum_main(wv.w, x2.y, x2.z, x2.w, y2.y, y2.z, y2.w, a);
}

__device__ __forceinline__ void accum_group_fall(float4 x0, float4 x1, float4 x2,
                                                 float4 y0, float4 y1, float4 y2, float* f) {
    accum_fall(x0.x, x0.y, x0.z, y0.x, y0.y, y0.z, f);
    accum_fall(x0.w, x1.x, x1.y, y0.w, y1.x, y1.y, f);
    accum_fall(x1.z, x1.w, x2.x, y1.z, y1.w, y2.x, f);
    accum_fall(x2.y, x2.z, x2.w, y2.y, y2.z, y2.w, f);
}

// tree-reduce NV values across the wave, then combine 4 waves in LDS.
// After this, sm[0][i]+sm[1][i]+sm[2][i]+sm[3][i] is the block total (t<NV reads it).
template <int NV>
__device__ __forceinline__ void block_reduce(float* v, float (*sm)[NACC], int t) {
    int wave = t >> 6, lane = t & 63;
    #pragma unroll
    for (int off = 32; off > 0; off >>= 1) {
        #pragma unroll
        for (int i = 0; i < NV; ++i) v[i] += __shfl_down(v[i], off, 64);
    }
    if (lane == 0) {
        #pragma unroll
        for (int i = 0; i < NV; ++i) sm[wave][i] = v[i];
    }
    __syncthreads();
}

__global__ __launch_bounds__(256) void kabsch_reduce(
    const float* __restrict__ c0, const float* __restrict__ c1,
    const float* __restrict__ w, int N, float* __restrict__ partials, int nblocks) {
    __shared__ float sm[4][NACC];

    float a[NMAIN];
    #pragma unroll
    for (int i = 0; i < NMAIN; ++i) a[i] = 0.0f;

    const int t = threadIdx.x;
    const int tid = blockIdx.x * blockDim.x + t;
    const int nthreads = gridDim.x * blockDim.x;
    const int ngroups = N >> 2;   // 4-point groups (48B -> 3 aligned float4s)
    const float4* A4 = (const float4*)c0;
    const float4* B4 = (const float4*)c1;
    const float4* W4 = (const float4*)w;

    // ---- 2-deep software-pipelined grid-stride loop over groups:
    // next iteration's 7 loads are issued before current iteration's compute.
    int g = tid;
    bool have = g < ngroups;
    float4 cw, ca0, ca1, ca2, cb0, cb1, cb2;
    if (have) {
        size_t b = (size_t)3 * (size_t)g;
        cw = W4[g];
        ca0 = A4[b]; ca1 = A4[b + 1]; ca2 = A4[b + 2];
        cb0 = B4[b]; cb1 = B4[b + 1]; cb2 = B4[b + 2];
    }
    while (have) {
        int gn = g + nthreads;
        bool haven = gn < ngroups;
        float4 nw, na0, na1, na2, nb0, nb1, nb2;
        if (haven) {
            size_t b = (size_t)3 * (size_t)gn;
            nw = W4[gn];
            na0 = A4[b]; na1 = A4[b + 1]; na2 = A4[b + 2];
            nb0 = B4[b]; nb1 = B4[b + 1]; nb2 = B4[b + 2];
        }
        accum_group_main(cw, ca0, ca1, ca2, cb0, cb1, cb2, a);
        cw = nw; ca0 = na0; ca1 = na1; ca2 = na2; cb0 = nb0; cb1 = nb1; cb2 = nb2;
        g = gn; have = haven;
    }
    if (tid == 0) {  // scalar tail (N % 4) — never taken for N = 4M
        for (int i = (ngroups << 2); i < N; ++i)
            accum_main(w[i], c0[3*i], c0[3*i+1], c0[3*i+2],
                       c1[3*i], c1[3*i+1], c1[3*i+2], a);
    }

    block_reduce<NMAIN>(a, sm, t);
    float blockCnt = sm[0][0] + sm[1][0] + sm[2][0] + sm[3][0];  // block-uniform
    if (t < NMAIN)
        partials[t * nblocks + blockIdx.x] =
            sm[0][t] + sm[1][t] + sm[2][t] + sm[3][t];

    // ---- fallback sums, only needed if global nonzero-weight count < 3.
    // If global count < 3 then EVERY block's local count < 3; a block with
    // local count >= 3 proves nep=false globally, so its fallback slots may
    // be anything summing benignly -> write zeros. Rare path re-reads from L2.
    if (blockCnt >= 3.0f) {
        __syncthreads();
        if (t < NFALL) partials[(NMAIN + t) * nblocks + blockIdx.x] = 0.0f;
        return;
    }
    float f[NFALL];
    #pragma unroll
    for (int i = 0; i < NFALL; ++i) f[i] = 0.0f;
    for (int gg = tid; gg < ngroups; gg += nthreads) {
        size_t b = (size_t)3 * (size_t)gg;
        accum_group_fall(A4[b], A4[b + 1], A4[b + 2],
                         B4[b], B4[b + 1], B4[b + 2], f);
    }
    if (tid == 0) {
        for (int i = (ngroups << 2); i < N; ++i)
            accum_fall(c0[3*i], c0[3*i+1], c0[3*i+2],
                       c1[3*i], c1[3*i+1], c1[3*i+2], f);
    }
    __syncthreads();
    block_reduce<NFALL>(f, sm, t);
    if (t < NFALL)
        partials[(NMAIN + t) * nblocks + blockIdx.x] =
            sm[0][t] + sm[1][t] + sm[2][t] + sm[3][t];
}

__device__ __forceinline__ double det3(const double m[3][3]) {
    return m[0][0] * (m[1][1] * m[2][2] - m[1][2] * m[2][1])
         - m[0][1] * (m[1][0] * m[2][2] - m[1][2] * m[2][0])
         + m[0][2] * (m[1][0] * m[2][1] - m[1][1] * m[2][0]);
}

__global__ __launch_bounds__(256) void kabsch_finalize(
    const float* __restrict__ partials, int nblocks, int N, float* __restrict__ out) {
    double d[NACC];
    #pragma unroll
    for (int i = 0; i < NACC; ++i) d[i] = 0.0;
    for (int m = threadIdx.x; m < nblocks; m += 256) {
        #pragma unroll
        for (int i = 0; i < NACC; ++i)
            d[i] += (double)partials[i * nblocks + m];   // lane-contiguous per i
    }
    #pragma unroll
    for (int off = 32; off > 0; off >>= 1) {
        #pragma unroll
        for (int i = 0; i < NACC; ++i) d[i] += __shfl_down(d[i], off, 64);
    }
    __shared__ double sm[4][NACC];
    int wave = threadIdx.x >> 6, lane = threadIdx.x & 63;
    if (lane == 0) {
        #pragma unroll
        for (int i = 0; i < NACC; ++i) sm[wave][i] = d[i];
    }
    __syncthreads();
    if (threadIdx.x != 0) return;
    #pragma unroll
    for (int i = 0; i < NACC; ++i) d[i] = sm[0][i] + sm[1][i] + sm[2][i] + sm[3][i];

    const double EPSF = (double)1.1920929e-7f;  // float32 eps
    double cnt = d[0];
    double W = d[1];
    double swx[3] = { d[2], d[3], d[4] };
    double swy[3] = { d[5], d[6], d[7] };
    double swyx[9];
    for (int i = 0; i < 9; ++i) swyx[i] = d[8 + i];
    bool nep = cnt < 3.0;
    if (nep) {  // weights += EPS everywhere, applied analytically via fallback sums
        W += EPSF * (double)N;
        for (int i = 0; i < 3; ++i) { swx[i] += EPSF * d[17 + i]; swy[i] += EPSF * d[20 + i]; }
        for (int i = 0; i < 9; ++i) swyx[i] += EPSF * d[23 + i];
    }

    double mx[3], my[3];
    for (int i = 0; i < 3; ++i) { mx[i] = swx[i] / W; my[i] = swy[i] / W; }
    double S[3][3];
    for (int o = 0; o < 3; ++o)
        for (int i = 0; i < 3; ++i)
            S[o][i] = swyx[o * 3 + i] / W - my[o] * mx[i];

    // Jacobi eigendecomposition of B = S^T S -> V, lam (6 cyclic sweeps)
    double Bm[3][3], V[3][3];
    for (int i = 0; i < 3; ++i)
        for (int j = 0; j < 3; ++j) {
            double acc = 0.0;
            for (int k = 0; k < 3; ++k) acc += S[k][i] * S[k][j];
            Bm[i][j] = acc;
            V[i][j] = (i == j) ? 1.0 : 0.0;
        }
    for (int sweep = 0; sweep < 6; ++sweep) {
        for (int pair = 0; pair < 3; ++pair) {
            int p = (pair == 2) ? 1 : 0;
            int q = (pair == 0) ? 1 : 2;
            double apq = Bm[p][q];
            if (fabs(apq) < 1e-300) continue;
            double theta = (Bm[q][q] - Bm[p][p]) / (2.0 * apq);
            double tt = ((theta >= 0.0) ? 1.0 : -1.0) / (fabs(theta) + sqrt(1.0 + theta * theta));
            double c = 1.0 / sqrt(1.0 + tt * tt);
            double sn = tt * c;
            for (int k = 0; k < 3; ++k) {
                double bkp = Bm[k][p], bkq = Bm[k][q];
                Bm[k][p] = c * bkp - sn * bkq;
                Bm[k][q] = sn * bkp + c * bkq;
            }
            for (int k = 0; k < 3; ++k) {
                double bpk = Bm[p][k], bqk = Bm[q][k];
                Bm[p][k] = c * bpk - sn * bqk;
                Bm[q][k] = sn * bpk + c * bqk;
            }
            for (int k = 0; k < 3; ++k) {
                double vkp = V[k][p], vkq = V[k][q];
                V[k][p] = c * vkp - sn * vkq;
                V[k][q] = sn * vkp + c * vkq;
            }
        }
    }
    double lam[3] = { Bm[0][0], Bm[1][1], Bm[2][2] };
    for (int i = 0; i < 2; ++i)
        for (int j = i + 1; j < 3; ++j)
            if (lam[j] > lam[i]) {
                double tl = lam[i]; lam[i] = lam[j]; lam[j] = tl;
                for (int k = 0; k < 3; ++k) { double tv = V[k][i]; V[k][i] = V[k][j]; V[k][j] = tv; }
            }
    double sig[3];
    for (int i = 0; i < 3; ++i) sig[i] = sqrt(fmax(lam[i], 0.0));

    double U[3][3];
    for (int i = 0; i < 3; ++i) {
        double u0 = S[0][0]*V[0][i] + S[0][1]*V[1][i] + S[0][2]*V[2][i];
        double u1 = S[1][0]*V[0][i] + S[1][1]*V[1][i] + S[1][2]*V[2][i];
        double u2 = S[2][0]*V[0][i] + S[2][1]*V[1][i] + S[2][2]*V[2][i];
        double nrm = sqrt(u0*u0 + u1*u1 + u2*u2);
        if (nrm > 1e-150) {
            U[0][i] = u0 / nrm; U[1][i] = u1 / nrm; U[2][i] = u2 / nrm;
        } else if (i == 0) {
            U[0][0] = 1.0; U[1][0] = 0.0; U[2][0] = 0.0;
        } else if (i == 1) {
            double e0 = (fabs(U[0][0]) < 0.9) ? 1.0 : 0.0;
            double e1 = 1.0 - e0;
            double dp = e0 * U[0][0] + e1 * U[1][0];
            double v0 = e0 - dp * U[0][0], v1 = e1 - dp * U[1][0], v2 = -dp * U[2][0];
            double n2 = sqrt(v0*v0 + v1*v1 + v2*v2);
            U[0][1] = v0 / n2; U[1][1] = v1 / n2; U[2][1] = v2 / n2;
        } else {
            U[0][2] = U[1][0]*U[2][1] - U[2][0]*U[1][1];
            U[1][2] = U[2][0]*U[0][1] - U[0][0]*U[2][1];
            U[2][2] = U[0][0]*U[1][1] - U[1][0]*U[0][1];
        }
    }

    double tol = sig[0] * 3.0 * EPSF;
    int rank = (sig[0] > tol) + (sig[1] > tol) + (sig[2] > tol);
    double detS = det3(S);
    double det_mul = det3(U) * det3(V);
    double sign_full = (detS < 0.0) ? -1.0 : 1.0;
    double sign_def = (fabs(det_mul + 1.0) <= 1.00001e-5) ? -1.0 : 1.0;
    double s = (rank > 2) ? sign_full : sign_def;

    double R[3][3];
    for (int o = 0; o < 3; ++o)
        for (int i = 0; i < 3; ++i)
            R[o][i] = U[o][0]*V[i][0] + U[o][1]*V[i][1] + s * U[o][2]*V[i][2];
    double tv[3];
    for (int o = 0; o < 3; ++o)
        tv[o] = my[o] - (R[o][0]*mx[0] + R[o][1]*mx[1] + R[o][2]*mx[2]);

    for (int o = 0; o < 3; ++o) {
        out[o * 4 + 0] = (float)R[o][0];
        out[o * 4 + 1] = (float)R[o][1];
        out[o * 4 + 2] = (float)R[o][2];
        out[o * 4 + 3] = (float)tv[o];
    }
    out[12] = 0.0f; out[13] = 0.0f; out[14] = 0.0f; out[15] = 1.0f;
    out[16] = nep ? 1.0f : 0.0f;
}

extern "C" void kernel_launch(void* const* d_in, const int* in_sizes, int n_in,
                              void* d_out, int out_size, void* d_ws, size_t ws_size,
                              hipStream_t stream) {
    const float* c0 = (const float*)d_in[0];
    const float* c1 = (const float*)d_in[1];
    const float* w  = (const float*)d_in[2];
    float* out = (float*)d_out;
    int N = in_sizes[2];  // B=1: weights has N elements

    int blocks = 2048;   // 8 blocks/CU queued; 2 pipelined group-iters/thread
    size_t need = (size_t)blocks * NACC * sizeof(float);
    if (need > ws_size) {
        blocks = (int)(ws_size / (NACC * sizeof(float)));
        if (blocks < 1) blocks = 1;
    }
    float* partials = (float*)d_ws;   // layout: [acc][block] (transposed)

    kabsch_reduce<<<blocks, 256, 0, stream>>>(c0, c1, w, N, partials, blocks);
    kabsch_finalize<<<1, 256, 0, stream>>>(partials, blocks, N, out);
}

// Round 6
// 154.533 us; speedup vs baseline: 1.0274x; 1.0091x over previous
//
#include <hip/hip_runtime.h>
#include <math.h>

#define NACC 32
#define TILE 1024          // points per tile: A=12KB, B=12KB per buffer
// partials layout (32 slots/block):
//  main (always valid):   0 cnt, 1 sw, 2-4 swx, 5-7 swy, 8-16 swyx[o*3+i]
//  fallback (valid only when block-local cnt<3, else zeros):
//                         17-19 sx, 20-22 sy, 23-31 syx[o*3+i]
#define NMAIN 17
#define NFALL 15

__device__ __forceinline__ void accum_main(float w, float x0, float x1, float x2,
                                           float y0, float y1, float y2, float* a) {
    a[0] += (w > 0.0f) ? 1.0f : 0.0f;
    a[1] += w;
    a[2] = fmaf(w, x0, a[2]); a[3] = fmaf(w, x1, a[3]); a[4] = fmaf(w, x2, a[4]);
    float wy0 = w * y0, wy1 = w * y1, wy2 = w * y2;
    a[5] += wy0; a[6] += wy1; a[7] += wy2;
    a[8]  = fmaf(wy0, x0, a[8]);  a[9]  = fmaf(wy0, x1, a[9]);  a[10] = fmaf(wy0, x2, a[10]);
    a[11] = fmaf(wy1, x0, a[11]); a[12] = fmaf(wy1, x1, a[12]); a[13] = fmaf(wy1, x2, a[13]);
    a[14] = fmaf(wy2, x0, a[14]); a[15] = fmaf(wy2, x1, a[15]); a[16] = fmaf(wy2, x2, a[16]);
}

__device__ __forceinline__ void accum_fall(float x0, float x1, float x2,
                                           float y0, float y1, float y2, float* f) {
    f[0] += x0; f[1] += x1; f[2] += x2;
    f[3] += y0; f[4] += y1; f[5] += y2;
    f[6]  = fmaf(y0, x0, f[6]);  f[7]  = fmaf(y0, x1, f[7]);  f[8]  = fmaf(y0, x2, f[8]);
    f[9]  = fmaf(y1, x0, f[9]);  f[10] = fmaf(y1, x1, f[10]); f[11] = fmaf(y1, x2, f[11]);
    f[12] = fmaf(y2, x0, f[12]); f[13] = fmaf(y2, x1, f[13]); f[14] = fmaf(y2, x2, f[14]);
}

__device__ __forceinline__ void accum_group_main(float4 wv, float4 x0, float4 x1, float4 x2,
                                                 float4 y0, float4 y1, float4 y2, float* a) {
    accum_main(wv.x, x0.x, x0.y, x0.z, y0.x, y0.y, y0.z, a);
    accum_main(wv.y, x0.w, x1.x, x1.y, y0.w, y1.x, y1.y, a);
    accum_main(wv.z, x1.z, x1.w, x2.x, y1.z, y1.w, y2.x, a);
    accum_main(wv.w, x2.y, x2.z, x2.w, y2.y, y2.z, y2.w, a);
}

__device__ __forceinline__ void accum_group_fall(float4 x0, float4 x1, float4 x2,
                                                 float4 y0, float4 y1, float4 y2, float* f) {
    accum_fall(x0.x, x0.y, x0.z, y0.x, y0.y, y0.z, f);
    accum_fall(x0.w, x1.x, x1.y, y0.w, y1.x, y1.y, f);
    accum_fall(x1.z, x1.w, x2.x, y1.z, y1.w, y2.x, f);
    accum_fall(x2.y, x2.z, x2.w, y2.y, y2.z, y2.w, f);
}

// async global->LDS DMA: one wave moves 64 lanes x 16B = 1KB, no VGPR return.
// lds dest must be wave-uniform; HW writes lane i at ldsbase + 16*i.
__device__ __forceinline__ void gl2lds16(const float* g_perlane, float* lds_uniform) {
    __builtin_amdgcn_global_load_lds(
        (const __attribute__((address_space(1))) void*)g_perlane,
        (__attribute__((address_space(3))) void*)lds_uniform,
        16, 0, 0);
}

template <int NV>
__device__ __forceinline__ void block_reduce(float* v, float (*sm)[NACC], int t) {
    int wave = t >> 6, lane = t & 63;
    #pragma unroll
    for (int off = 32; off > 0; off >>= 1) {
        #pragma unroll
        for (int i = 0; i < NV; ++i) v[i] += __shfl_down(v[i], off, 64);
    }
    if (lane == 0) {
        #pragma unroll
        for (int i = 0; i < NV; ++i) sm[wave][i] = v[i];
    }
    __syncthreads();
}

__global__ __launch_bounds__(256) void kabsch_reduce(
    const float* __restrict__ c0, const float* __restrict__ c1,
    const float* __restrict__ w, int N, float* __restrict__ partials, int nblocks) {
    __shared__ float sA[2][TILE * 3];   // 2 x 12KB
    __shared__ float sB[2][TILE * 3];   // 2 x 12KB
    __shared__ float sm[4][NACC];

    float a[NMAIN];
    #pragma unroll
    for (int i = 0; i < NMAIN; ++i) a[i] = 0.0f;

    const int t = threadIdx.x;
    const int wave = t >> 6, lane = t & 63;
    const int ntiles = N >> 10;
    const float4* W4 = (const float4*)w;

    // ---- double-buffered DMA pipeline over tiles (grid-stride) ----
    int k = blockIdx.x;
    bool have = k < ntiles;
    int buf = 0;
    float4 wcur;
    if (have) {
        const float* ga = c0 + (size_t)k * 3072;
        const float* gb = c1 + (size_t)k * 3072;
        #pragma unroll
        for (int c = 0; c < 3; ++c) {
            int chunk = wave * 3 + c;          // this wave's 1KB chunks
            gl2lds16(ga + chunk * 256 + lane * 4, &sA[0][chunk * 256]);
            gl2lds16(gb + chunk * 256 + lane * 4, &sB[0][chunk * 256]);
        }
        wcur = W4[(size_t)k * 256 + t];
    }
    while (have) {   // `have` is block-uniform -> barrier safe
        int kn = k + gridDim.x;
        bool haven = kn < ntiles;
        __syncthreads();   // drains DMA for tile k (vmcnt before barrier)
        float4 wnext;
        if (haven) {       // prefetch tile k+stride into other buffer (async)
            const float* ga = c0 + (size_t)kn * 3072;
            const float* gb = c1 + (size_t)kn * 3072;
            #pragma unroll
            for (int c = 0; c < 3; ++c) {
                int chunk = wave * 3 + c;
                gl2lds16(ga + chunk * 256 + lane * 4, &sA[buf ^ 1][chunk * 256]);
                gl2lds16(gb + chunk * 256 + lane * 4, &sB[buf ^ 1][chunk * 256]);
            }
            wnext = W4[(size_t)kn * 256 + t];
        }
        // compute tile k from LDS: thread t owns points 4t..4t+3 (48B, 16B-aligned)
        {
            const float4* pa = (const float4*)(&sA[buf][t * 12]);
            const float4* pb = (const float4*)(&sB[buf][t * 12]);
            float4 xa0 = pa[0], xa1 = pa[1], xa2 = pa[2];
            float4 xb0 = pb[0], xb1 = pb[1], xb2 = pb[2];
            accum_group_main(wcur, xa0, xa1, xa2, xb0, xb1, xb2, a);
        }
        wcur = wnext; k = kn; have = haven; buf ^= 1;
    }
    if (blockIdx.x == 0 && t == 0) {  // scalar tail (N % 1024) — 0 for N=4M
        for (int i = ntiles << 10; i < N; ++i)
            accum_main(w[i], c0[3*i], c0[3*i+1], c0[3*i+2],
                       c1[3*i], c1[3*i+1], c1[3*i+2], a);
    }

    __syncthreads();
    block_reduce<NMAIN>(a, sm, t);
    float blockCnt = sm[0][0] + sm[1][0] + sm[2][0] + sm[3][0];  // block-uniform
    if (t < NMAIN)
        partials[t * nblocks + blockIdx.x] =
            sm[0][t] + sm[1][t] + sm[2][t] + sm[3][t];

    // ---- fallback sums, only needed if global nonzero-weight count < 3.
    // A block with local count >= 3 proves nep=false globally -> write zeros.
    if (blockCnt >= 3.0f) {
        __syncthreads();
        if (t < NFALL) partials[(NMAIN + t) * nblocks + blockIdx.x] = 0.0f;
        return;
    }
    float f[NFALL];
    #pragma unroll
    for (int i = 0; i < NFALL; ++i) f[i] = 0.0f;
    const int tid = blockIdx.x * blockDim.x + t;
    const int nthreads = gridDim.x * blockDim.x;
    const int ngroups = N >> 2;
    const float4* A4 = (const float4*)c0;
    const float4* B4 = (const float4*)c1;
    for (int gg = tid; gg < ngroups; gg += nthreads) {
        size_t b = (size_t)3 * (size_t)gg;
        accum_group_fall(A4[b], A4[b + 1], A4[b + 2],
                         B4[b], B4[b + 1], B4[b + 2], f);
    }
    if (tid == 0) {
        for (int i = (ngroups << 2); i < N; ++i)
            accum_fall(c0[3*i], c0[3*i+1], c0[3*i+2],
                       c1[3*i], c1[3*i+1], c1[3*i+2], f);
    }
    __syncthreads();
    block_reduce<NFALL>(f, sm, t);
    if (t < NFALL)
        partials[(NMAIN + t) * nblocks + blockIdx.x] =
            sm[0][t] + sm[1][t] + sm[2][t] + sm[3][t];
}

__device__ __forceinline__ double det3(const double m[3][3]) {
    return m[0][0] * (m[1][1] * m[2][2] - m[1][2] * m[2][1])
         - m[0][1] * (m[1][0] * m[2][2] - m[1][2] * m[2][0])
         + m[0][2] * (m[1][0] * m[2][1] - m[1][1] * m[2][0]);
}

__global__ __launch_bounds__(256) void kabsch_finalize(
    const float* __restrict__ partials, int nblocks, int N, float* __restrict__ out) {
    double d[NACC];
    #pragma unroll
    for (int i = 0; i < NACC; ++i) d[i] = 0.0;
    for (int m = threadIdx.x; m < nblocks; m += 256) {
        #pragma unroll
        for (int i = 0; i < NACC; ++i)
            d[i] += (double)partials[i * nblocks + m];   // lane-contiguous per i
    }
    #pragma unroll
    for (int off = 32; off > 0; off >>= 1) {
        #pragma unroll
        for (int i = 0; i < NACC; ++i) d[i] += __shfl_down(d[i], off, 64);
    }
    __shared__ double sm[4][NACC];
    int wave = threadIdx.x >> 6, lane = threadIdx.x & 63;
    if (lane == 0) {
        #pragma unroll
        for (int i = 0; i < NACC; ++i) sm[wave][i] = d[i];
    }
    __syncthreads();
    if (threadIdx.x != 0) return;
    #pragma unroll
    for (int i = 0; i < NACC; ++i) d[i] = sm[0][i] + sm[1][i] + sm[2][i] + sm[3][i];

    const double EPSF = (double)1.1920929e-7f;  // float32 eps
    double cnt = d[0];
    double W = d[1];
    double swx[3] = { d[2], d[3], d[4] };
    double swy[3] = { d[5], d[6], d[7] };
    double swyx[9];
    for (int i = 0; i < 9; ++i) swyx[i] = d[8 + i];
    bool nep = cnt < 3.0;
    if (nep) {  // weights += EPS everywhere, applied analytically via fallback sums
        W += EPSF * (double)N;
        for (int i = 0; i < 3; ++i) { swx[i] += EPSF * d[17 + i]; swy[i] += EPSF * d[20 + i]; }
        for (int i = 0; i < 9; ++i) swyx[i] += EPSF * d[23 + i];
    }

    double mx[3], my[3];
    for (int i = 0; i < 3; ++i) { mx[i] = swx[i] / W; my[i] = swy[i] / W; }
    double S[3][3];
    for (int o = 0; o < 3; ++o)
        for (int i = 0; i < 3; ++i)
            S[o][i] = swyx[o * 3 + i] / W - my[o] * mx[i];

    // Jacobi eigendecomposition of B = S^T S -> V, lam (6 cyclic sweeps)
    double Bm[3][3], V[3][3];
    for (int i = 0; i < 3; ++i)
        for (int j = 0; j < 3; ++j) {
            double acc = 0.0;
            for (int k = 0; k < 3; ++k) acc += S[k][i] * S[k][j];
            Bm[i][j] = acc;
            V[i][j] = (i == j) ? 1.0 : 0.0;
        }
    for (int sweep = 0; sweep < 6; ++sweep) {
        for (int pair = 0; pair < 3; ++pair) {
            int p = (pair == 2) ? 1 : 0;
            int q = (pair == 0) ? 1 : 2;
            double apq = Bm[p][q];
            if (fabs(apq) < 1e-300) continue;
            double theta = (Bm[q][q] - Bm[p][p]) / (2.0 * apq);
            double tt = ((theta >= 0.0) ? 1.0 : -1.0) / (fabs(theta) + sqrt(1.0 + theta * theta));
            double c = 1.0 / sqrt(1.0 + tt * tt);
            double sn = tt * c;
            for (int k = 0; k < 3; ++k) {
                double bkp = Bm[k][p], bkq = Bm[k][q];
                Bm[k][p] = c * bkp - sn * bkq;
                Bm[k][q] = sn * bkp + c * bkq;
            }
            for (int k = 0; k < 3; ++k) {
                double bpk = Bm[p][k], bqk = Bm[q][k];
                Bm[p][k] = c * bpk - sn * bqk;
                Bm[q][k] = sn * bpk + c * bqk;
            }
            for (int k = 0; k < 3; ++k) {
                double vkp = V[k][p], vkq = V[k][q];
                V[k][p] = c * vkp - sn * vkq;
                V[k][q] = sn * vkp + c * vkq;
            }
        }
    }
    double lam[3] = { Bm[0][0], Bm[1][1], Bm[2][2] };
    for (int i = 0; i < 2; ++i)
        for (int j = i + 1; j < 3; ++j)
            if (lam[j] > lam[i]) {
                double tl = lam[i]; lam[i] = lam[j]; lam[j] = tl;
                for (int k = 0; k < 3; ++k) { double tv = V[k][i]; V[k][i] = V[k][j]; V[k][j] = tv; }
            }
    double sig[3];
    for (int i = 0; i < 3; ++i) sig[i] = sqrt(fmax(lam[i], 0.0));

    double U[3][3];
    for (int i = 0; i < 3; ++i) {
        double u0 = S[0][0]*V[0][i] + S[0][1]*V[1][i] + S[0][2]*V[2][i];
        double u1 = S[1][0]*V[0][i] + S[1][1]*V[1][i] + S[1][2]*V[2][i];
        double u2 = S[2][0]*V[0][i] + S[2][1]*V[1][i] + S[2][2]*V[2][i];
        double nrm = sqrt(u0*u0 + u1*u1 + u2*u2);
        if (nrm > 1e-150) {
            U[0][i] = u0 / nrm; U[1][i] = u1 / nrm; U[2][i] = u2 / nrm;
        } else if (i == 0) {
            U[0][0] = 1.0; U[1][0] = 0.0; U[2][0] = 0.0;
        } else if (i == 1) {
            double e0 = (fabs(U[0][0]) < 0.9) ? 1.0 : 0.0;
            double e1 = 1.0 - e0;
            double dp = e0 * U[0][0] + e1 * U[1][0];
            double v0 = e0 - dp * U[0][0], v1 = e1 - dp * U[1][0], v2 = -dp * U[2][0];
            double n2 = sqrt(v0*v0 + v1*v1 + v2*v2);
            U[0][1] = v0 / n2; U[1][1] = v1 / n2; U[2][1] = v2 / n2;
        } else {
            U[0][2] = U[1][0]*U[2][1] - U[2][0]*U[1][1];
            U[1][2] = U[2][0]*U[0][1] - U[0][0]*U[2][1];
            U[2][2] = U[0][0]*U[1][1] - U[1][0]*U[0][1];
        }
    }

    double tol = sig[0] * 3.0 * EPSF;
    int rank = (sig[0] > tol) + (sig[1] > tol) + (sig[2] > tol);
    double detS = det3(S);
    double det_mul = det3(U) * det3(V);
    double sign_full = (detS < 0.0) ? -1.0 : 1.0;
    double sign_def = (fabs(det_mul + 1.0) <= 1.00001e-5) ? -1.0 : 1.0;
    double s = (rank > 2) ? sign_full : sign_def;

    double R[3][3];
    for (int o = 0; o < 3; ++o)
        for (int i = 0; i < 3; ++i)
            R[o][i] = U[o][0]*V[i][0] + U[o][1]*V[i][1] + s * U[o][2]*V[i][2];
    double tv[3];
    for (int o = 0; o < 3; ++o)
        tv[o] = my[o] - (R[o][0]*mx[0] + R[o][1]*mx[1] + R[o][2]*mx[2]);

    for (int o = 0; o < 3; ++o) {
        out[o * 4 + 0] = (float)R[o][0];
        out[o * 4 + 1] = (float)R[o][1];
        out[o * 4 + 2] = (float)R[o][2];
        out[o * 4 + 3] = (float)tv[o];
    }
    out[12] = 0.0f; out[13] = 0.0f; out[14] = 0.0f; out[15] = 1.0f;
    out[16] = nep ? 1.0f : 0.0f;
}

extern "C" void kernel_launch(void* const* d_in, const int* in_sizes, int n_in,
                              void* d_out, int out_size, void* d_ws, size_t ws_size,
                              hipStream_t stream) {
    const float* c0 = (const float*)d_in[0];
    const float* c1 = (const float*)d_in[1];
    const float* w  = (const float*)d_in[2];
    float* out = (float*)d_out;
    int N = in_sizes[2];  // B=1: weights has N elements

    int blocks = 768;   // 3 blocks/CU (48KB LDS each), DMA double-buffered tiles
    size_t need = (size_t)blocks * NACC * sizeof(float);
    if (need > ws_size) {
        blocks = (int)(ws_size / (NACC * sizeof(float)));
        if (blocks < 1) blocks = 1;
    }
    float* partials = (float*)d_ws;   // layout: [acc][block] (transposed)

    kabsch_reduce<<<blocks, 256, 0, stream>>>(c0, c1, w, N, partials, blocks);
    kabsch_finalize<<<1, 256, 0, stream>>>(partials, blocks, N, out);
}